// Round 3
// baseline (1614.953 us; speedup 1.0000x reference)
//
#include <hip/hip_runtime.h>
#include <hip/hip_bf16.h>
#include <math.h>

typedef __bf16 bf16;
typedef __bf16 bf16x8 __attribute__((ext_vector_type(8)));
typedef float  f32x4  __attribute__((ext_vector_type(4)));

#define DEV __device__ __forceinline__

DEV f32x4 mfma16(bf16x8 a, bf16x8 b, f32x4 c) {
    return __builtin_amdgcn_mfma_f32_16x16x32_bf16(a, b, c, 0, 0, 0);
}

// ---------------------------------------------------------------------------
// Generic bf16 GEMM: C[M x N] = A[M x K] @ Bt[N x K]^T (+fp32 bias).
// m93-style staging: global uint4 -> VGPR -> ds_write_b128, [128][32] tiles.
// MODE 0: Cb = acc + bias (bf16 out, ldC stride)
// MODE 1: Cb = gelu(acc + bias)
// MODE 2: Cf += acc + bias (fp32 residual accumulate)
// ---------------------------------------------------------------------------
template <int MODE>
__global__ __launch_bounds__(256, 2) void gemm_k(
    const bf16* __restrict__ A, const bf16* __restrict__ Bt,
    const float* __restrict__ bias, bf16* __restrict__ Cb,
    float* __restrict__ Cf, int K, int ldC)
{
    __shared__ bf16 As[128 * 32];
    __shared__ bf16 Bs[128 * 32];
    const int tid  = threadIdx.x;
    const int lane = tid & 63;
    const int w    = tid >> 6;
    const int wm   = w & 1, wn = w >> 1;
    const long tm  = (long)blockIdx.y * 128;
    const long tn  = (long)blockIdx.x * 128;

    f32x4 acc[4][4] = {};

    // staging positions: position p covers row p>>2, 16B chunk p&3
    const int p0 = tid, p1 = tid + 256;
    const int r0 = p0 >> 2, c0 = (p0 & 3) * 8;
    const int r1 = p1 >> 2, c1 = (p1 & 3) * 8;
    const bf16* A0 = A + (tm + r0) * K + c0;
    const bf16* A1 = A + (tm + r1) * K + c1;
    const bf16* B0 = Bt + (tn + r0) * K + c0;
    const bf16* B1 = Bt + (tn + r1) * K + c1;

    // fragment read offsets (elements)
    int am[4], bn[4];
#pragma unroll
    for (int i = 0; i < 4; ++i) {
        int ra = wm * 64 + i * 16 + (lane & 15);
        am[i]  = ra * 32 + (lane >> 4) * 8;
        int rb = wn * 64 + i * 16 + (lane & 15);
        bn[i]  = rb * 32 + (lane >> 4) * 8;
    }

    for (int k0 = 0; k0 < K; k0 += 32) {
        uint4 va0 = *(const uint4*)(A0 + k0);
        uint4 va1 = *(const uint4*)(A1 + k0);
        uint4 vb0 = *(const uint4*)(B0 + k0);
        uint4 vb1 = *(const uint4*)(B1 + k0);
        __syncthreads();   // previous iteration's ds_reads complete
        *(uint4*)&As[p0 * 8] = va0;
        *(uint4*)&As[p1 * 8] = va1;
        *(uint4*)&Bs[p0 * 8] = vb0;
        *(uint4*)&Bs[p1 * 8] = vb1;
        __syncthreads();
        bf16x8 a[4], b[4];
#pragma unroll
        for (int i = 0; i < 4; ++i) a[i] = *(const bf16x8*)&As[am[i]];
#pragma unroll
        for (int i = 0; i < 4; ++i) b[i] = *(const bf16x8*)&Bs[bn[i]];
#pragma unroll
        for (int mi = 0; mi < 4; ++mi)
#pragma unroll
            for (int ni = 0; ni < 4; ++ni)
                acc[mi][ni] = mfma16(a[mi], b[ni], acc[mi][ni]);
    }

#pragma unroll
    for (int mi = 0; mi < 4; ++mi) {
        const long rbase = tm + wm * 64 + mi * 16 + ((lane >> 4) << 2);
#pragma unroll
        for (int ni = 0; ni < 4; ++ni) {
            const long col = tn + wn * 64 + ni * 16 + (lane & 15);
            const float bv = bias[col];
#pragma unroll
            for (int r = 0; r < 4; ++r) {
                float v = acc[mi][ni][r] + bv;
                if constexpr (MODE == 1)
                    v = 0.5f * v * (1.0f + erff(v * 0.70710678118654752f));
                const long idx = (rbase + r) * (long)ldC + col;
                if constexpr (MODE == 2) Cf[idx] += v;
                else                     Cb[idx] = (bf16)v;
            }
        }
    }
}

// ---------------------------------------------------------------------------
// Attention: one block per (b, h, 64-row q tile). 4 waves; wave w handles
// 16 q rows. K staged [256][72] (pad 8, b128-clean), P reuses K region
// [w][16][264], V^T staged in two 32-d halves [32][264]. Bias is fp32.
// ---------------------------------------------------------------------------
__global__ __launch_bounds__(256, 2) void attn_k(
    const bf16* __restrict__ qkv, const float* __restrict__ bias,
    bf16* __restrict__ ctx)
{
    __shared__ bf16 smem[256 * 72 + 32 * 264];
    bf16* Ks = smem;
    bf16* Vt = smem + 256 * 72;

    const int tid = threadIdx.x, lane = tid & 63, w = tid >> 6;
    const int qt = blockIdx.x & 3;
    const int h  = (blockIdx.x >> 2) & 7;
    const int b  = blockIdx.x >> 5;
    const long qkv_base = (long)b * 256 * 1536;

    // stage K rows [n][d], padded stride 72
#pragma unroll
    for (int i = 0; i < 8; ++i) {
        int p = i * 256 + tid;
        int n = p >> 3, kk = (p & 7) * 8;
        uint4 v = *(const uint4*)(qkv + qkv_base + (long)n * 1536 + 512 + h * 64 + kk);
        *(uint4*)&Ks[n * 72 + kk] = v;
    }
    // stage V^T half 0: Vt[d][n], d in [0,32)
    {
        int d = tid & 31, nb = tid >> 5;
#pragma unroll 4
        for (int i = 0; i < 32; ++i) {
            int n = nb + i * 8;
            Vt[d * 264 + n] = qkv[qkv_base + (long)n * 1536 + 1024 + h * 64 + d];
        }
    }

    // q fragments (global, already scaled by D^-0.5 via folded wq)
    const int qr0 = qt * 64 + w * 16;
    bf16x8 aq0, aq1;
    {
        const bf16* g = qkv + qkv_base + (long)(qr0 + (lane & 15)) * 1536 + h * 64 + ((lane >> 4) * 8);
        aq0 = *(const bf16x8*)g;
        aq1 = *(const bf16x8*)(g + 32);
    }
    __syncthreads();

    // scores = q @ k^T + bias (bias preloaded into accumulator)
    f32x4 s[16];
    const float* bb = bias + (((long)(b * 8 + h)) * 256 + qr0) * 256;
#pragma unroll
    for (int ct = 0; ct < 16; ++ct) {
        const int col = ct * 16 + (lane & 15);
        f32x4 c;
#pragma unroll
        for (int r = 0; r < 4; ++r)
            c[r] = bb[(long)((lane >> 4) * 4 + r) * 256 + col];
        bf16x8 k0 = *(const bf16x8*)&Ks[(ct * 16 + (lane & 15)) * 72 + ((lane >> 4) * 8)];
        bf16x8 k1 = *(const bf16x8*)&Ks[(ct * 16 + (lane & 15)) * 72 + 32 + ((lane >> 4) * 8)];
        c = mfma16(aq0, k0, c);
        c = mfma16(aq1, k1, c);
        s[ct] = c;
    }

    // softmax over 256 cols; row = (lane>>4)*4 + r, 16-lane groups share a row
    float m[4] = {-1e30f, -1e30f, -1e30f, -1e30f};
#pragma unroll
    for (int ct = 0; ct < 16; ++ct)
#pragma unroll
        for (int r = 0; r < 4; ++r) m[r] = fmaxf(m[r], s[ct][r]);
#pragma unroll
    for (int r = 0; r < 4; ++r)
#pragma unroll
        for (int off = 1; off < 16; off <<= 1)
            m[r] = fmaxf(m[r], __shfl_xor(m[r], off));
    float l[4] = {0.f, 0.f, 0.f, 0.f};
#pragma unroll
    for (int ct = 0; ct < 16; ++ct)
#pragma unroll
        for (int r = 0; r < 4; ++r) {
            float p = __expf(s[ct][r] - m[r]);
            s[ct][r] = p;
            l[r] += p;
        }
#pragma unroll
    for (int r = 0; r < 4; ++r) {
#pragma unroll
        for (int off = 1; off < 16; off <<= 1) l[r] += __shfl_xor(l[r], off);
        l[r] = 1.0f / l[r];
    }

    __syncthreads();  // all waves done reading Ks -> safe to overwrite with P
    bf16* P = Ks + w * (16 * 264);
#pragma unroll
    for (int ct = 0; ct < 16; ++ct)
#pragma unroll
        for (int r = 0; r < 4; ++r)
            P[(long)((lane >> 4) * 4 + r) * 264 + ct * 16 + (lane & 15)] = (bf16)s[ct][r];

    // P as A-operand fragments (own wave's region; same-wave LDS RAW is
    // in-order on CDNA DS pipe)
    bf16x8 ap[8];
#pragma unroll
    for (int nk = 0; nk < 8; ++nk)
        ap[nk] = *(const bf16x8*)&P[(lane & 15) * 264 + nk * 32 + (lane >> 4) * 8];

    f32x4 o[4];
#pragma unroll
    for (int dt = 0; dt < 2; ++dt) {
        f32x4 c = {};
#pragma unroll
        for (int nk = 0; nk < 8; ++nk) {
            bf16x8 bv = *(const bf16x8*)&Vt[(dt * 16 + (lane & 15)) * 264 + nk * 32 + (lane >> 4) * 8];
            c = mfma16(ap[nk], bv, c);
        }
        o[dt] = c;
    }

    __syncthreads();  // all waves done with V half 0
    {
        int d = tid & 31, nb = tid >> 5;
#pragma unroll 4
        for (int i = 0; i < 32; ++i) {
            int n = nb + i * 8;
            Vt[d * 264 + n] = qkv[qkv_base + (long)n * 1536 + 1024 + h * 64 + 32 + d];
        }
    }
    __syncthreads();
#pragma unroll
    for (int dt = 0; dt < 2; ++dt) {
        f32x4 c = {};
#pragma unroll
        for (int nk = 0; nk < 8; ++nk) {
            bf16x8 bv = *(const bf16x8*)&Vt[(dt * 16 + (lane & 15)) * 264 + nk * 32 + (lane >> 4) * 8];
            c = mfma16(ap[nk], bv, c);
        }
        o[2 + dt] = c;
    }

#pragma unroll
    for (int dt = 0; dt < 4; ++dt) {
        const int col = h * 64 + dt * 16 + (lane & 15);
#pragma unroll
        for (int r = 0; r < 4; ++r) {
            const long row = (long)b * 256 + qr0 + (lane >> 4) * 4 + r;
            ctx[row * 512 + col] = (bf16)(o[dt][r] * l[r]);
        }
    }
}

// ---------------------------------------------------------------------------
// LayerNorm: fp32 input rows of 512, fp32 scale/bias, bf16 out. 1 wave/row.
// ---------------------------------------------------------------------------
__global__ __launch_bounds__(256) void ln_k(
    const float* __restrict__ x, const float* __restrict__ sc,
    const float* __restrict__ bi, bf16* __restrict__ y)
{
    const int lane = threadIdx.x & 63;
    const long row = (long)blockIdx.x * 4 + (threadIdx.x >> 6);
    const float* xr = x + row * 512;
    float v[8];
    *(float4*)&v[0] = ((const float4*)xr)[lane * 2];
    *(float4*)&v[4] = ((const float4*)xr)[lane * 2 + 1];
    float sum = 0.f;
#pragma unroll
    for (int j = 0; j < 8; ++j) sum += v[j];
#pragma unroll
    for (int off = 1; off < 64; off <<= 1) sum += __shfl_xor(sum, off);
    const float mu = sum * (1.0f / 512.0f);
    float sq = 0.f;
#pragma unroll
    for (int j = 0; j < 8; ++j) { float d = v[j] - mu; sq += d * d; }
#pragma unroll
    for (int off = 1; off < 64; off <<= 1) sq += __shfl_xor(sq, off);
    const float rs = rsqrtf(sq * (1.0f / 512.0f) + 1e-5f);
    bf16* yr = y + row * 512;
#pragma unroll
    for (int j = 0; j < 8; ++j) {
        int c = lane * 8 + j;
        yr[c] = (bf16)((v[j] - mu) * rs * sc[c] + bi[c]);
    }
}

// ---------------------------------------------------------------------------
// One-shot weight transpose fp32 -> bf16 [N][K] layout (q-scale folded).
// blockIdx: layer*3072 + {wq:0-255, wk:256-511, wv:512-767, wo:768-1023,
//                         w1:1024-2047, w2:2048-3071}, 32x32 tiles.
// ---------------------------------------------------------------------------
__global__ __launch_bounds__(256) void transpose_k(
    const float* __restrict__ wq, const float* __restrict__ wk,
    const float* __restrict__ wv, const float* __restrict__ wo,
    const float* __restrict__ w1, const float* __restrict__ w2,
    bf16* __restrict__ qkvT, bf16* __restrict__ woT,
    bf16* __restrict__ w1T, bf16* __restrict__ w2T)
{
    __shared__ float tile[32][33];
    const int tid = threadIdx.x, tx = tid & 31, ty = tid >> 5;
    const int l = blockIdx.x / 3072;
    const int r = blockIdx.x % 3072;

    const float* In = nullptr;
    bf16* Out = nullptr;
    int Nd, tk, tn, rowOff = 0, ldO;
    float scale = 1.0f;
    if (r < 1024) {
        const int which = r >> 8, t = r & 255;
        tn = t >> 4; tk = t & 15; Nd = 512; ldO = 512;
        const long woff = (long)l * 512 * 512;
        if (which == 0)      { In = wq + woff; Out = qkvT + (long)l * 1536 * 512; rowOff = 0;    scale = 0.125f; }
        else if (which == 1) { In = wk + woff; Out = qkvT + (long)l * 1536 * 512; rowOff = 512;  }
        else if (which == 2) { In = wv + woff; Out = qkvT + (long)l * 1536 * 512; rowOff = 1024; }
        else                 { In = wo + woff; Out = woT + woff; }
    } else if (r < 2048) {
        const int t = r - 1024;
        tn = t >> 4; tk = t & 15; Nd = 2048; ldO = 512;
        In = w1 + (long)l * 512 * 2048; Out = w1T + (long)l * 2048 * 512;
    } else {
        const int t = r - 2048;
        tn = t & 15; tk = t >> 4; Nd = 512; ldO = 2048;
        In = w2 + (long)l * 2048 * 512; Out = w2T + (long)l * 512 * 2048;
    }
    const int gk = tk * 32, gn = tn * 32;
#pragma unroll
    for (int j = 0; j < 4; ++j) {
        int rr = ty + j * 8;
        tile[rr][tx] = In[(long)(gk + rr) * Nd + gn + tx] * scale;
    }
    __syncthreads();
#pragma unroll
    for (int j = 0; j < 4; ++j) {
        int rr = ty + j * 8;
        Out[(long)(rowOff + gn + rr) * ldO + gk + tx] = (bf16)tile[tx][rr];
    }
}

__global__ void biasq_k(const float* __restrict__ bq, const float* __restrict__ bk,
                        const float* __restrict__ bv, float* __restrict__ bqkv)
{
    int i = blockIdx.x * 256 + threadIdx.x;
    if (i >= 8 * 1536) return;
    int l = i / 1536, j = i % 1536;
    float v;
    if (j < 512)       v = bq[l * 512 + j] * 0.125f;
    else if (j < 1024) v = bk[l * 512 + j - 512];
    else               v = bv[l * 512 + j - 1024];
    bqkv[i] = v;
}

// ---------------------------------------------------------------------------
extern "C" void kernel_launch(void* const* d_in, const int* in_sizes, int n_in,
                              void* d_out, int out_size, void* d_ws, size_t ws_size,
                              hipStream_t stream)
{
    (void)in_sizes; (void)n_in; (void)out_size; (void)ws_size;
    const float* x    = (const float*)d_in[0];
    const float* ab   = (const float*)d_in[1];
    const float* ln1s = (const float*)d_in[2];
    const float* ln1b = (const float*)d_in[3];
    const float* wq   = (const float*)d_in[4];
    const float* bq   = (const float*)d_in[5];
    const float* wk   = (const float*)d_in[6];
    const float* bk   = (const float*)d_in[7];
    const float* wv   = (const float*)d_in[8];
    const float* bv   = (const float*)d_in[9];
    const float* wo   = (const float*)d_in[10];
    const float* bo   = (const float*)d_in[11];
    const float* ln2s = (const float*)d_in[12];
    const float* ln2b = (const float*)d_in[13];
    const float* w1   = (const float*)d_in[14];
    const float* b1   = (const float*)d_in[15];
    const float* w2   = (const float*)d_in[16];
    const float* b2   = (const float*)d_in[17];

    char* ws = (char*)d_ws;
    // layout (bytes):
    // [0, 16M)        xf    fp32 residual stream [8192][512]
    // [16M, 24M)      y/ctx bf16 [8192][512]   (disjoint lifetimes)
    // [24M, 58M)      qkv/ffn bf16 (qkv [8192][1536] / ffn [8192][2048], disjoint)
    // [58M, ~108M)    transposed bf16 weights + fp32 fused qkv bias
    float* xf   = (float*)ws;
    bf16* y     = (bf16*)(ws + 16777216);
    bf16* ctx   = y;
    bf16* qkv   = (bf16*)(ws + 16777216 + 8388608);
    bf16* ffn   = qkv;
    bf16* wqkvT = (bf16*)(ws + 16777216 + 8388608 + 33554432);
    bf16* woT   = wqkvT + (long)8 * 1536 * 512;
    bf16* w1T   = woT + (long)8 * 512 * 512;
    bf16* w2T   = w1T + (long)8 * 2048 * 512;
    float* bqkv = (float*)(w2T + (long)8 * 512 * 2048);

    hipMemcpyAsync(xf, x, (size_t)8192 * 512 * 4, hipMemcpyDeviceToDevice, stream);
    transpose_k<<<24576, 256, 0, stream>>>(wq, wk, wv, wo, w1, w2, wqkvT, woT, w1T, w2T);
    biasq_k<<<48, 256, 0, stream>>>(bq, bk, bv, bqkv);

    for (int l = 0; l < 8; ++l) {
        ln_k<<<2048, 256, 0, stream>>>(xf, ln1s + l * 512, ln1b + l * 512, y);
        gemm_k<0><<<dim3(12, 64), 256, 0, stream>>>(
            y, wqkvT + (long)l * 1536 * 512, bqkv + l * 1536, qkv, nullptr, 512, 1536);
        attn_k<<<1024, 256, 0, stream>>>(qkv, ab, ctx);
        gemm_k<2><<<dim3(4, 64), 256, 0, stream>>>(
            ctx, woT + (long)l * 512 * 512, bo + l * 512, nullptr, xf, 512, 512);
        ln_k<<<2048, 256, 0, stream>>>(xf, ln2s + l * 512, ln2b + l * 512, y);
        gemm_k<1><<<dim3(16, 64), 256, 0, stream>>>(
            y, w1T + (long)l * 2048 * 512, b1 + l * 2048, ffn, nullptr, 512, 2048);
        gemm_k<2><<<dim3(4, 64), 256, 0, stream>>>(
            ffn, w2T + (long)l * 512 * 2048, b2 + l * 512, nullptr, xf, 2048, 512);
    }
    hipMemcpyAsync(d_out, xf, (size_t)8192 * 512 * 4, hipMemcpyDeviceToDevice, stream);
}